// Round 2
// baseline (86.601 us; speedup 1.0000x reference)
//
#include <hip/hip_runtime.h>

typedef float f32x4 __attribute__((ext_vector_type(4)));
typedef _Float16 half8 __attribute__((ext_vector_type(8)));

#define NEG 0.2f

// ---------------------------------------------------------------------------
// K1: Wh = nf @ W^T (f32), s1 = Wh@a1, s2 = Wh@a2 (exact f32),
//     per-block max(s2) -> smax slots, Wh -> fp16 transposed [b][o][j].
// grid 256 = 8 batches x 32 row-blocks of 64 rows; block 256 (4 waves).
// ---------------------------------------------------------------------------
__global__ __launch_bounds__(256) void gat_wh_kernel(
    const float* __restrict__ nf, const float* __restrict__ W,
    const float* __restrict__ a, _Float16* __restrict__ whT,
    float* __restrict__ s1g, float* __restrict__ s2g, float* __restrict__ smax)
{
    const int b    = blockIdx.x >> 5;
    const int rb   = blockIdx.x & 31;
    const int row0 = rb * 64;
    const int t    = threadIdx.x;
    const int lane = t & 63;
    const int wv   = t >> 6;

    __shared__ _Float16 whL[64][72];   // [row][o], pad to 72 to spread banks
    __shared__ float    wred[4];

    // W row (o = lane) in registers: 64 VGPRs
    f32x4 Wreg[16];
    const float* wp = W + lane * 64;
#pragma unroll
    for (int i = 0; i < 16; ++i) Wreg[i] = *(const f32x4*)(wp + i * 4);
    const float a1v = a[lane];
    const float a2v = a[64 + lane];

    const float* nfb = nf + ((long)b * 2048 + row0) * 64;
    float wmax = -3.0e38f;

    for (int g = 0; g < 16; ++g) {
        const int row = g * 4 + wv;
        const f32x4* nfp = (const f32x4*)(nfb + row * 64);  // same addr across wave -> broadcast
        f32x4 acc = {0.f, 0.f, 0.f, 0.f};
#pragma unroll
        for (int i = 0; i < 16; ++i) acc += nfp[i] * Wreg[i];
        const float wh = acc.x + acc.y + acc.z + acc.w;     // Wh[row][lane]
        whL[row][lane] = (_Float16)wh;
        float p1 = wh * a1v;
        float p2 = wh * a2v;
#pragma unroll
        for (int m = 32; m >= 1; m >>= 1) {
            p1 += __shfl_xor(p1, m);
            p2 += __shfl_xor(p2, m);
        }
        if (lane == 0) {
            s1g[b * 2048 + row0 + row] = p1;
            s2g[b * 2048 + row0 + row] = p2;
            wmax = fmaxf(wmax, p2);
        }
    }
    if (lane == 0) wred[wv] = wmax;
    __syncthreads();
    if (t == 0)
        smax[blockIdx.x] = fmaxf(fmaxf(wred[0], wred[1]), fmaxf(wred[2], wred[3]));

    // transpose out: whT[(b*64+o)*2048 + row0 + j]
    const int o = t >> 2;
    const int part = t & 3;
    unsigned int tmp[8];
#pragma unroll
    for (int kk = 0; kk < 8; ++kk) {
        const int j = part * 16 + kk * 2;
        unsigned int lo = *(const unsigned short*)&whL[j][o];
        unsigned int hi = *(const unsigned short*)&whL[j + 1][o];
        tmp[kk] = lo | (hi << 16);
    }
    uint4 v0, v1;
    v0.x = tmp[0]; v0.y = tmp[1]; v0.z = tmp[2]; v0.w = tmp[3];
    v1.x = tmp[4]; v1.y = tmp[5]; v1.z = tmp[6]; v1.w = tmp[7];
    _Float16* dst = whT + ((long)(b * 64 + o) * 2048 + row0 + part * 16);
    *(uint4*)dst = v0;
    *(uint4*)(dst + 8) = v1;
}

// ---------------------------------------------------------------------------
// K2: barrier-free K loop. Per block: 32 rows. 4 waves: h = wv&1 row-half,
//     cq = wv>>1 col-quarter (32 cols of out0). Per 64-col chunk:
//       - P computed directly in MFMA A-fragment layout (8 exps per frag)
//       - f32 P stored nontemporally to global attention (wave stores kc==cq)
//       - B fragments loaded straight from whT (L2-resident, 16B/lane)
//       - 4x mfma_f32_16x16x32_f16
// grid 512 = 8 batches x 64 row-blocks of 32; block 256 (4 waves).
// ---------------------------------------------------------------------------
__global__ __launch_bounds__(256) void gat_attn_kernel(
    const _Float16* __restrict__ whT, const float* __restrict__ s1g,
    const float* __restrict__ s2g, const float* __restrict__ smax,
    float* __restrict__ outp)
{
    const int b    = blockIdx.x >> 6;
    const int rb   = blockIdx.x & 63;
    const int i0   = rb * 32;
    const int t    = threadIdx.x;
    const int lane = t & 63;
    const int wv   = t >> 6;

    __shared__ __attribute__((aligned(16))) float s2sh[2048];
    __shared__ float s1sh[32], Msh[32], iDsh[32];
    __shared__ float m2sh;

    // ---- phase 0: stage s2 (full batch row), s1 tile, m2 = max(s2) ----
#pragma unroll
    for (int k = 0; k < 8; ++k) s2sh[t + k * 256] = s2g[b * 2048 + t + k * 256];
    if (t < 32) {
        s1sh[t] = s1g[b * 2048 + i0 + t];
        float v = smax[b * 32 + t];
#pragma unroll
        for (int m = 16; m >= 1; m >>= 1) v = fmaxf(v, __shfl_xor(v, m));
        if (t == 0) m2sh = v;
    }
    __syncthreads();

    // ---- phase 1: denominators. M_i = lrelu(s1_i + max_j s2_j) exactly ----
    {
        const float m2  = m2sh;
        const int   r   = t >> 3, q = t & 7;
        const float s1r = s1sh[r];
        const float xm  = s1r + m2;
        const float M   = fmaxf(xm, NEG * xm);
        float acc = 0.f;
        for (int j = q; j < 2048; j += 8) {
            float x = s1r + s2sh[j];
            float e = fmaxf(x, NEG * x);
            acc += __expf(e - M);
        }
        acc += __shfl_xor(acc, 1);
        acc += __shfl_xor(acc, 2);
        acc += __shfl_xor(acc, 4);
        if (q == 0) { Msh[r] = M; iDsh[r] = 1.0f / acc; }
    }
    __syncthreads();

    // ---- phase 2: barrier-free K loop ----
    const int h    = wv & 1;            // row half (16 rows)
    const int cq   = wv >> 1;           // col quarter (32 cols) + store half sel
    const int mloc = h * 16 + (lane & 15);
    const int g    = lane >> 4;         // k-group within fragment
    const float s1r = s1sh[mloc];
    const float Mr  = Msh[mloc];
    const float iDr = iDsh[mloc];

    f32x4 acc0 = {0.f, 0.f, 0.f, 0.f}, acc1 = {0.f, 0.f, 0.f, 0.f};
    const _Float16* Bb0 = whT + (long)b * 64 * 2048 + (long)(cq * 32 + (lane & 15)) * 2048 + g * 8;
    const _Float16* Bb1 = Bb0 + 16 * 2048;
    float* attnr = outp + 1048576 + ((long)b * 2048 + i0 + mloc) * 2048 + cq * 32 + g * 8;
    const float* s2p = &s2sh[g * 8];

    for (int c = 0; c < 32; ++c) {
        const int j0 = c * 64;
        // B fragments straight from global (L2-resident)
        half8 b00 = *(const half8*)(Bb0 + j0);
        half8 b01 = *(const half8*)(Bb1 + j0);
        half8 b10 = *(const half8*)(Bb0 + j0 + 32);
        half8 b11 = *(const half8*)(Bb1 + j0 + 32);

        // A fragments (P values) for kc=0,1 computed in-register
        f32x4 sa0 = *(const f32x4*)(s2p + j0);
        f32x4 sa1 = *(const f32x4*)(s2p + j0 + 4);
        f32x4 sb0 = *(const f32x4*)(s2p + j0 + 32);
        f32x4 sb1 = *(const f32x4*)(s2p + j0 + 36);
        f32x4 p00, p01, p10, p11;
        half8 a0, a1;
#pragma unroll
        for (int e = 0; e < 4; ++e) {
            float x, lr, p;
            x = s1r + sa0[e]; lr = fmaxf(x, NEG * x);
            p = __expf(lr - Mr) * iDr; p00[e] = p; a0[e] = (_Float16)p;
            x = s1r + sa1[e]; lr = fmaxf(x, NEG * x);
            p = __expf(lr - Mr) * iDr; p01[e] = p; a0[e + 4] = (_Float16)p;
            x = s1r + sb0[e]; lr = fmaxf(x, NEG * x);
            p = __expf(lr - Mr) * iDr; p10[e] = p; a1[e] = (_Float16)p;
            x = s1r + sb1[e]; lr = fmaxf(x, NEG * x);
            p = __expf(lr - Mr) * iDr; p11[e] = p; a1[e + 4] = (_Float16)p;
        }

        // attention store: wave stores the kc==cq half (each value once)
        if (cq == 0) {
            __builtin_nontemporal_store(p00, (f32x4*)(attnr + j0));
            __builtin_nontemporal_store(p01, (f32x4*)(attnr + j0 + 4));
        } else {
            __builtin_nontemporal_store(p10, (f32x4*)(attnr + j0));  // attnr already has +cq*32
            __builtin_nontemporal_store(p11, (f32x4*)(attnr + j0 + 4));
        }

        acc0 = __builtin_amdgcn_mfma_f32_16x16x32_f16(a0, b00, acc0, 0, 0, 0);
        acc1 = __builtin_amdgcn_mfma_f32_16x16x32_f16(a0, b01, acc1, 0, 0, 0);
        acc0 = __builtin_amdgcn_mfma_f32_16x16x32_f16(a1, b10, acc0, 0, 0, 0);
        acc1 = __builtin_amdgcn_mfma_f32_16x16x32_f16(a1, b11, acc1, 0, 0, 0);
    }

    // ---- epilogue: elu, write out0 (wave owns rows h*16.., cols cq*32..) ----
    {
        const int col = cq * 32 + (lane & 15);
        const int rg  = lane >> 4;
        float* ob = outp + ((long)b * 2048 + i0 + h * 16 + rg * 4) * 64 + col;
#pragma unroll
        for (int r = 0; r < 4; ++r) {
            float x = acc0[r];
            ob[(long)r * 64] = (x > 0.f) ? x : (__expf(x) - 1.0f);
            float y = acc1[r];
            ob[(long)r * 64 + 16] = (y > 0.f) ? y : (__expf(y) - 1.0f);
        }
    }
}

extern "C" void kernel_launch(void* const* d_in, const int* in_sizes, int n_in,
                              void* d_out, int out_size, void* d_ws, size_t ws_size,
                              hipStream_t stream)
{
    (void)in_sizes; (void)n_in; (void)out_size; (void)ws_size;
    const float* nf = (const float*)d_in[0];
    const float* W  = (const float*)d_in[1];
    const float* a  = (const float*)d_in[2];
    float* outp = (float*)d_out;

    char* ws = (char*)d_ws;
    _Float16* whT = (_Float16*)ws;                         // 2 MB: [8][64][2048] fp16
    float* s1g  = (float*)(ws + 2097152);                  // 64 KB
    float* s2g  = (float*)(ws + 2097152 + 65536);          // 64 KB
    float* smax = (float*)(ws + 2097152 + 131072);         // 256 slots

    gat_wh_kernel<<<256, 256, 0, stream>>>(nf, W, a, whT, s1g, s2g, smax);
    gat_attn_kernel<<<512, 256, 0, stream>>>(whT, s1g, s2g, smax, outp);
}

// Round 3
// 72.621 us; speedup vs baseline: 1.1925x; 1.1925x over previous
//
#include <hip/hip_runtime.h>

typedef float f32x4 __attribute__((ext_vector_type(4)));
typedef _Float16 half8 __attribute__((ext_vector_type(8)));

#define NEG 0.2f

// ---------------------------------------------------------------------------
// K1: Wh = nf @ W^T (f32), s1 = Wh@a1, s2 = Wh@a2 (exact f32),
//     per-block max(s2) -> smax slots, Wh -> fp16 transposed [b][o][j].
// grid 256 = 8 batches x 32 row-blocks of 64 rows; block 256 (4 waves).
// ---------------------------------------------------------------------------
__global__ __launch_bounds__(256) void gat_wh_kernel(
    const float* __restrict__ nf, const float* __restrict__ W,
    const float* __restrict__ a, _Float16* __restrict__ whT,
    float* __restrict__ s1g, float* __restrict__ s2g, float* __restrict__ smax)
{
    const int b    = blockIdx.x >> 5;
    const int rb   = blockIdx.x & 31;
    const int row0 = rb * 64;
    const int t    = threadIdx.x;
    const int lane = t & 63;
    const int wv   = t >> 6;

    __shared__ _Float16 whL[64][72];   // [row][o], pad to 72 to spread banks
    __shared__ float    wred[4];

    // W row (o = lane) in registers: 64 VGPRs
    f32x4 Wreg[16];
    const float* wp = W + lane * 64;
#pragma unroll
    for (int i = 0; i < 16; ++i) Wreg[i] = *(const f32x4*)(wp + i * 4);
    const float a1v = a[lane];
    const float a2v = a[64 + lane];

    const float* nfb = nf + ((long)b * 2048 + row0) * 64;
    float wmax = -3.0e38f;

    for (int g = 0; g < 16; ++g) {
        const int row = g * 4 + wv;
        const f32x4* nfp = (const f32x4*)(nfb + row * 64);  // same addr across wave -> broadcast
        f32x4 acc = {0.f, 0.f, 0.f, 0.f};
#pragma unroll
        for (int i = 0; i < 16; ++i) acc += nfp[i] * Wreg[i];
        const float wh = acc.x + acc.y + acc.z + acc.w;     // Wh[row][lane]
        whL[row][lane] = (_Float16)wh;
        float p1 = wh * a1v;
        float p2 = wh * a2v;
#pragma unroll
        for (int m = 32; m >= 1; m >>= 1) {
            p1 += __shfl_xor(p1, m);
            p2 += __shfl_xor(p2, m);
        }
        if (lane == 0) {
            s1g[b * 2048 + row0 + row] = p1;
            s2g[b * 2048 + row0 + row] = p2;
            wmax = fmaxf(wmax, p2);
        }
    }
    if (lane == 0) wred[wv] = wmax;
    __syncthreads();
    if (t == 0)
        smax[blockIdx.x] = fmaxf(fmaxf(wred[0], wred[1]), fmaxf(wred[2], wred[3]));

    // transpose out: whT[(b*64+o)*2048 + row0 + j]
    const int o = t >> 2;
    const int part = t & 3;
    unsigned int tmp[8];
#pragma unroll
    for (int kk = 0; kk < 8; ++kk) {
        const int j = part * 16 + kk * 2;
        unsigned int lo = *(const unsigned short*)&whL[j][o];
        unsigned int hi = *(const unsigned short*)&whL[j + 1][o];
        tmp[kk] = lo | (hi << 16);
    }
    uint4 v0, v1;
    v0.x = tmp[0]; v0.y = tmp[1]; v0.z = tmp[2]; v0.w = tmp[3];
    v1.x = tmp[4]; v1.y = tmp[5]; v1.z = tmp[6]; v1.w = tmp[7];
    _Float16* dst = whT + ((long)(b * 64 + o) * 2048 + row0 + part * 16);
    *(uint4*)dst = v0;
    *(uint4*)(dst + 8) = v1;
}

// ---------------------------------------------------------------------------
// K2: 16-row blocks (1024 blocks = 4/CU). Per 64-col chunk:
//     - wave wv computes P rows wv*4..wv*4+3 (4 exps/lane, no duplication)
//     - coalesced f32 attention stores (256B per row)
//     - P -> double-buffered LDS fp16 (one barrier per chunk)
//     - B fragments straight from L2-resident whT
//     - 2x mfma_f32_16x16x32_f16 per wave (out cols wv*16..wv*16+15)
// ---------------------------------------------------------------------------
__global__ __launch_bounds__(256) void gat_attn_kernel(
    const _Float16* __restrict__ whT, const float* __restrict__ s1g,
    const float* __restrict__ s2g, const float* __restrict__ smax,
    float* __restrict__ outp)
{
    const int b    = blockIdx.x >> 7;
    const int rb   = blockIdx.x & 127;
    const int i0   = rb * 16;
    const int t    = threadIdx.x;
    const int lane = t & 63;
    const int wv   = t >> 6;

    __shared__ __attribute__((aligned(16))) float s2sh[2048];
    __shared__ float s1sh[16], Msh[16], iDsh[16];
    __shared__ float m2sh;
    __shared__ __attribute__((aligned(16))) _Float16 Pl[2][16][72];

    // ---- phase 0: stage s2 (full batch row), s1 tile, m2 = max(s2) ----
#pragma unroll
    for (int k = 0; k < 8; ++k) s2sh[t + k * 256] = s2g[b * 2048 + t + k * 256];
    if (t < 16) s1sh[t] = s1g[b * 2048 + i0 + t];
    if (t < 32) {
        float v = smax[b * 32 + t];
#pragma unroll
        for (int m = 16; m >= 1; m >>= 1) v = fmaxf(v, __shfl_xor(v, m));
        if (t == 0) m2sh = v;
    }
    __syncthreads();

    // ---- phase 1: denominators. M_i = lrelu(s1_i + max_j s2_j) exactly ----
    {
        const float m2  = m2sh;
        const int   r   = t >> 4, q = t & 15;
        const float s1r = s1sh[r];
        const float xm  = s1r + m2;
        const float M   = fmaxf(xm, NEG * xm);
        float acc = 0.f;
        for (int j = q; j < 2048; j += 16) {
            float x = s1r + s2sh[j];
            float e = fmaxf(x, NEG * x);
            acc += __expf(e - M);
        }
        acc += __shfl_xor(acc, 1);
        acc += __shfl_xor(acc, 2);
        acc += __shfl_xor(acc, 4);
        acc += __shfl_xor(acc, 8);
        if (q == 0) { Msh[r] = M; iDsh[r] = 1.0f / acc; }
    }
    __syncthreads();

    // per-wave constants for its 4 P rows
    float s1v[4], Mv[4], iDv[4];
#pragma unroll
    for (int k = 0; k < 4; ++k) {
        s1v[k] = s1sh[wv * 4 + k];
        Mv[k]  = Msh[wv * 4 + k];
        iDv[k] = iDsh[wv * 4 + k];
    }

    // ---- phase 2: K loop, one barrier per chunk (double-buffered Pl) ----
    f32x4 acc0 = {0.f, 0.f, 0.f, 0.f};
    const int koff = (lane >> 4) * 8;
    const _Float16* Bp = whT + (long)b * 64 * 2048
                       + (long)(wv * 16 + (lane & 15)) * 2048 + koff;
    float* attnb = outp + 1048576 + ((long)b * 2048 + i0 + wv * 4) * 2048;

    for (int c = 0; c < 32; ++c) {
        const int j0  = c * 64;
        const int buf = c & 1;

        // B fragments (independent of Pl; issue early)
        half8 b0 = *(const half8*)(Bp + j0);
        half8 b1 = *(const half8*)(Bp + j0 + 32);

        // P: 4 rows x 64 cols per wave, each value once; coalesced stores
        const float sv = s2sh[j0 + lane];
#pragma unroll
        for (int k = 0; k < 4; ++k) {
            float x = s1v[k] + sv;
            float e = fmaxf(x, NEG * x);
            float p = __expf(e - Mv[k]) * iDv[k];
            attnb[(long)k * 2048 + j0 + lane] = p;
            Pl[buf][wv * 4 + k][lane] = (_Float16)p;
        }
        __syncthreads();

        half8 a0 = *(const half8*)&Pl[buf][lane & 15][koff];
        half8 a1 = *(const half8*)&Pl[buf][lane & 15][koff + 32];
        acc0 = __builtin_amdgcn_mfma_f32_16x16x32_f16(a0, b0, acc0, 0, 0, 0);
        acc0 = __builtin_amdgcn_mfma_f32_16x16x32_f16(a1, b1, acc0, 0, 0, 0);
    }

    // ---- epilogue: elu, write out0 (wave owns cols wv*16..wv*16+15) ----
    {
        const int col = wv * 16 + (lane & 15);
        float* ob = outp + ((long)b * 2048 + i0 + (lane >> 4) * 4) * 64 + col;
#pragma unroll
        for (int r = 0; r < 4; ++r) {
            float x = acc0[r];
            ob[(long)r * 64] = (x > 0.f) ? x : (__expf(x) - 1.0f);
        }
    }
}

extern "C" void kernel_launch(void* const* d_in, const int* in_sizes, int n_in,
                              void* d_out, int out_size, void* d_ws, size_t ws_size,
                              hipStream_t stream)
{
    (void)in_sizes; (void)n_in; (void)out_size; (void)ws_size;
    const float* nf = (const float*)d_in[0];
    const float* W  = (const float*)d_in[1];
    const float* a  = (const float*)d_in[2];
    float* outp = (float*)d_out;

    char* ws = (char*)d_ws;
    _Float16* whT = (_Float16*)ws;                         // 2 MB: [8][64][2048] fp16
    float* s1g  = (float*)(ws + 2097152);                  // 64 KB
    float* s2g  = (float*)(ws + 2097152 + 65536);          // 64 KB
    float* smax = (float*)(ws + 2097152 + 131072);         // 256 slots

    gat_wh_kernel<<<256, 256, 0, stream>>>(nf, W, a, whT, s1g, s2g, smax);
    gat_attn_kernel<<<1024, 256, 0, stream>>>(whT, s1g, s2g, smax, outp);
}